// Round 21
// baseline (151.427 us; speedup 1.0000x reference)
//
#include <hip/hip_runtime.h>
#include <cstdint>

// XLA emits separate mul/add; contraction off by default. Hot paths use
// explicit fmaf()/hw-transcendentals — measured-safe across 17 rounds
// (absmax pinned at 3.36e7 vs threshold 4.76e34 for r8-r20's variants).
#pragma clang fp contract(off)

#define TSAVES 49
#define SPSAVE 100
#define NB 8192
#define TRAJ 32                    // trajectories per block
#define NGENW 14                   // gen waves (all but CHAIN_WV, SI_WV)
#define CHAIN_WV 12                // r0-chain wave  (SIMD0)
#define SI_WV 13                   // s,i+summarize wave (SIMD1)
#define NDEPTH 6                   // noise ring depth (gen run-ahead)

// Per-wave gen-unit counts, nibble-packed, w0 in low nibble; waves 12,13 = 0.
// SIMD s hosts waves {s,s+4,s+8,s+12}: S0 {0,4,8}=11 (+chain), S1 {1,5,9}=10
// (+si), S2 {2,6,10,14}=15, S3 {3,7,11,15}=14. LP-optimal split of 50 units
// x 190cy + chain-issue 600cy + si-issue 800cy -> max SIMD ~2850 cy (r19
// measured: S3=13u+si=3270 was critical at group 3375; r20 proved merging
// chain+si into one wave serializes — revert to two sim waves, rebalance).
#define CNTPACK 0x3300343344344444ULL

typedef float f32x4 __attribute__((ext_vector_type(4)));

__device__ __forceinline__ uint32_t rotl32(uint32_t v, int d) {
  return __builtin_rotateleft32(v, (uint32_t)d);
}

// JAX threefry2x32, 20 rounds.
__device__ __forceinline__ void tf2x32(uint32_t k0, uint32_t k1,
                                       uint32_t x0, uint32_t x1,
                                       uint32_t& o0, uint32_t& o1) {
  uint32_t ks2 = k0 ^ k1 ^ 0x1BD11BDAu;
#define TF_ROUND(r) { x0 += x1; x1 = rotl32(x1, r); x1 ^= x0; }
  x0 += k0; x1 += k1;
  TF_ROUND(13) TF_ROUND(15) TF_ROUND(26) TF_ROUND(6)
  x0 += k1; x1 += ks2 + 1u;
  TF_ROUND(17) TF_ROUND(29) TF_ROUND(16) TF_ROUND(24)
  x0 += ks2; x1 += k0 + 2u;
  TF_ROUND(13) TF_ROUND(15) TF_ROUND(26) TF_ROUND(6)
  x0 += k0; x1 += k1 + 3u;
  TF_ROUND(17) TF_ROUND(29) TF_ROUND(16) TF_ROUND(24)
  x0 += k1; x1 += ks2 + 4u;
  TF_ROUND(13) TF_ROUND(15) TF_ROUND(26) TF_ROUND(6)
  x0 += ks2; x1 += k0 + 5u;
#undef TF_ROUND
  o0 = x0; o1 = x1;
}

// jax.random.split(key(seed)), jax_threefry_partitionable=True (fold-like).
__device__ __forceinline__ void derive_keys(int seed, uint32_t& kn0, uint32_t& kn1,
                                            uint32_t& ku0, uint32_t& ku1) {
  uint64_t sv = (uint64_t)(int64_t)seed;
  uint32_t k0 = (uint32_t)(sv >> 32);
  uint32_t k1 = (uint32_t)(sv & 0xffffffffULL);
  tf2x32(k0, k1, 0u, 0u, kn0, kn1);  // keys[0] = k_noise
  tf2x32(k0, k1, 0u, 1u, ku0, ku1);  // keys[1] = k_u
}

// partitionable random_bits(32): counter = (hi=0, lo=n); bits = y0 ^ y1.
__device__ __forceinline__ uint32_t rand_bits32(uint32_t k0, uint32_t k1, uint32_t n) {
  uint32_t y0, y1;
  tf2x32(k0, k1, 0u, n, y0, y1);
  return y0 ^ y1;
}

// bits -> erfinv-core p*u (XLA ErfInv32/Giles). Caller multiplies by
// cpv = (0.1*sqrt(2))*pvol — validated bit-compatible since r8.
__device__ __forceinline__ float bits_to_eu(uint32_t bits) {
#pragma clang fp contract(fast)
  float u01 = __uint_as_float((bits >> 9) | 0x3f800000u) - 1.0f;
  float u = u01 * 2.0f + (-0.99999994f);
  u = fmaxf(-0.99999994f, u);
  float omu2 = 1.0f - u * u;                       // fma(-u,u,1)
  float w = -(__builtin_amdgcn_logf(omu2) * 0.6931472f);  // v_log (log2) * ln2
  float p;
  if (w < 5.0f) {
    float z = w - 2.5f;
    p = 2.81022636e-08f;
    p = 3.43273939e-07f + p * z;
    p = -3.5233877e-06f + p * z;
    p = -4.39150654e-06f + p * z;
    p = 0.00021858087f + p * z;
    p = -0.00125372503f + p * z;
    p = -0.00417768164f + p * z;
    p = 0.246640727f + p * z;
    p = 1.50140941f + p * z;
  } else {
    float z = __builtin_amdgcn_sqrtf(w) - 3.0f;
    p = -0.000200214257f;
    p = 0.000100950558f + p * z;
    p = 0.00134934322f + p * z;
    p = -0.00367342844f + p * z;
    p = 0.00573950773f + p * z;
    p = -0.0076224613f + p * z;
    p = 0.00943887047f + p * z;
    p = 1.00167406f + p * z;
    p = 2.83297682f + p * z;
  }
  return p * u;
}

__device__ __forceinline__ float clip_param(float x) {
  return fminf(0.99999988f, fmaxf(1e-07f, x));
}

// Fused, barrier-free, static schedule, SIMD-rebalanced (see CNTPACK note).
// 256 blocks x 16 waves: 14 gen + chain wave (12, S0) + si wave (13, S1).
// Gen fills 6-deep LDS noise ring; chain writes exiting-r0 to 2-deep rbuf;
// si consumes rbuf. Monotone counters + s_sleep (r15/r17/r19-validated).
__global__ __launch_bounds__(1024) void fused_kernel(const float* __restrict__ cond,
                                                     const int* __restrict__ seedp,
                                                     float* __restrict__ out) {
  __shared__ f32x4 nbuf[NDEPTH][25][TRAJ];  // 76.8 KiB: noise ring
  __shared__ f32x4 rbuf[2][25][TRAJ];       // 25.6 KiB: exiting-r0, 2 groups
  __shared__ int done[TSAVES];              // gen waves finished with group g (of 14)
  __shared__ int r0cnt, sicnt;

  const int tid = threadIdx.x;
  const int lane = tid & 63;
  const int wv = tid >> 6;
  const int bbase = blockIdx.x * TRAJ;
  const int tr = lane & 31;
  const int h = lane >> 5;              // gen: e-parity selector
  const int b = bbase + tr;

  if (tid < TSAVES) done[tid] = 0;
  if (tid == 0) { r0cnt = 0; sicnt = 0; }
  __syncthreads();

  volatile int* vdone = done;
  volatile int* vr0 = &r0cnt;
  volatile int* vsi = &sicnt;

  uint32_t kn0, kn1, ku0, ku1;
  derive_keys(seedp[0], kn0, kn1, ku0, ku1);

  float pinf = clip_param(cond[b * 4 + 0]);
  float prec = clip_param(cond[b * 4 + 1]);
  float pmr  = clip_param(cond[b * 4 + 2]);
  float pvol = clip_param(cond[b * 4 + 3]);
  const float r0m  = pinf / prec;
  const float dtmr = 0.01f * pmr;
  const float c4 = 1.0f - dtmr;
  const float a4 = dtmr * r0m;
  const float c2 = 0.01f * prec;
  const float c3 = 1.0f - c2;
  const float c3p4 = (c3 * c3) * (c3 * c3);
  const float cpv = 0.14142136f * pvol;     // 0.1*sqrt(2) folded (r8+)

  if (wv != CHAIN_WV && wv != SI_WV) {
    // -------- producers: rebalanced static units (see CNTPACK) --------
    const int cnt = (int)((CNTPACK >> (4 * wv)) & 0xFULL);
    int off = 0;
#pragma unroll
    for (int w = 0; w < 16; ++w) if (w < wv) off += (int)((CNTPACK >> (4 * w)) & 0xFULL);
    for (int g = 0; g <= 48; ++g) {
      if (g >= NDEPTH) {                   // ring slot free when chain did g-NDEPTH
        while (*vr0 < g - (NDEPTH - 1)) __builtin_amdgcn_s_sleep(1);
      }
      const uint32_t nbase = (uint32_t)(g * SPSAVE) * (uint32_t)NB + (uint32_t)b;
      float* nb = (float*)&nbuf[g % NDEPTH][0][0];
      for (int k = 0; k < cnt; ++k) {
        const int id = off + k;            // 0..49 chunk-halves
        const int c = id >> 1;
        const int e = ((id & 1) << 1) | h;
        uint32_t n = nbase + (uint32_t)(4 * c + e) * (uint32_t)NB;
        float eu = bits_to_eu(rand_bits32(kn0, kn1, n));
        nb[(c * 32 + tr) * 4 + e] = eu * cpv;
      }
      __threadfence_block();               // drain ds_writes before signaling
      if (lane == 0) atomicAdd(&done[g], 1);
    }
  } else if (wv == CHAIN_WV) {
    // -------- r0 chain (serial latency floor; lightly-loaded SIMD0) --------
    float r0 = r0m;
    for (int g = 0; g <= 48; ++g) {
      while (vdone[g] < NGENW) __builtin_amdgcn_s_sleep(1);
      if (g >= 2) {                        // rbuf[g&1] reusable when si did g-2
        while (*vsi < g - 1) __builtin_amdgcn_s_sleep(1);
      }
      __threadfence_block();               // acquire
      const int sn = g % NDEPTH, sr = g & 1;
      f32x4 vd = nbuf[sn][0][tr];
#pragma unroll
      for (int c = 0; c < 25; ++c) {
        f32x4 vdn = (c < 24) ? nbuf[sn][c + 1][tr] : vd;  // prefetch next
        f32x4 w;
#pragma unroll
        for (int e = 0; e < 4; ++e) {
          float sq  = __builtin_amdgcn_sqrtf(fabsf(r0));
          float r0h = fmaf(c4, r0, a4);
          r0 = fmaf(sq, vd[e], r0h);
          w[e] = r0;                        // exiting r0
        }
        rbuf[sr][c][tr] = w;
        vd = vdn;
      }
      __threadfence_block();               // release
      if (lane == 0) *vr0 = g + 1;
    }
  } else {
    // -------- s,i + streaming summarize (SIMD1) --------
    float s = 0.99f, i = 0.01f, r0in = r0m;
    float best = -1.0f; int bi = 0;
    float plg = 0.0f, sd = 0.0f, sd2 = 0.0f;
    for (int g = 0; g <= 48; ++g) {
      while (*vr0 < g + 1) __builtin_amdgcn_s_sleep(1);
      __threadfence_block();               // acquire
      const int sr = g & 1;
      f32x4 rv = rbuf[sr][0][tr];
#pragma unroll
      for (int c = 0; c < 25; ++c) {
        f32x4 rvn = (c < 24) ? rbuf[sr][c + 1][tr] : rv;  // prefetch next
        float rs0 = r0in * s;  s = fmaf(-c2, rs0, s);
        float rs1 = rv[0] * s; s = fmaf(-c2, rs1, s);
        float rs2 = rv[1] * s; s = fmaf(-c2, rs2, s);
        float rs3 = rv[2] * s; s = fmaf(-c2, rs3, s);
        float hh = fmaf(c3, rs0, rs1);
        hh = fmaf(c3, hh, rs2);
        hh = fmaf(c3, hh, rs3);
        i = fmaf(c3p4, i, c2 * hh);
        r0in = rv[3];
        rv = rvn;
      }
      float v = i;
      if (!isfinite(v)) v = 0.0f;
      float x = fmaxf(v, 1e-05f);
      if (x > best) { best = x; bi = g; }
      float lg = __builtin_amdgcn_logf(x) * 0.6931472f;
      if (g > 0) { float d = lg - plg; sd += d; sd2 += d * d; }
      plg = lg;
      __threadfence_block();               // release (done reading rbuf[sr])
      if (lane == 0) *vsi = g + 1;
    }
    if (lane < TRAJ) {
      uint32_t ub = rand_bits32(ku0, ku1, (uint32_t)b);
      float u = __uint_as_float((ub >> 9) | 0x3f800000u) - 1.0f;
      u = fmaxf(0.0f, u);
      float maxat = ((float)bi + u) / 49.0f;
      float mean = sd / 48.0f;
      float var = sd2 / 48.0f - mean * mean;
      float stdv = sqrtf(fmaxf(var, 0.0f));
      out[b * 3 + 0] = (best  - 0.38f) / 0.14f;
      out[b * 3 + 1] = (maxat - 0.21f) / 0.12f;
      out[b * 3 + 2] = (stdv  - 0.14f) / 0.03f;
    }
  }
}

extern "C" void kernel_launch(void* const* d_in, const int* in_sizes, int n_in,
                              void* d_out, int out_size, void* d_ws, size_t ws_size,
                              hipStream_t stream) {
  const float* cond = (const float*)d_in[0];
  const int* seedp = (const int*)d_in[1];
  float* out = (float*)d_out;
  (void)d_ws; (void)ws_size;   // fully LDS-resident: no workspace needed
  fused_kernel<<<NB / TRAJ, 1024, 0, stream>>>(cond, seedp, out);
}

// Round 22
// 143.267 us; speedup vs baseline: 1.0570x; 1.0570x over previous
//
#include <hip/hip_runtime.h>
#include <cstdint>

// XLA emits separate mul/add; contraction off by default. Hot paths use
// explicit fmaf()/hw-transcendentals — measured-safe across 18 rounds
// (absmax pinned at 3.36e7 vs threshold 4.76e34 for r8-r21's variants).
#pragma clang fp contract(off)

#define TSAVES 49
#define SPSAVE 100
#define NB 8192
#define TRAJ 32                    // trajectories per block
#define GENW 14                    // noise-generator waves per block
#define NDEPTH 6                   // noise ring depth (gen run-ahead)

// Per-wave gen-unit counts, nibble-packed, w0 in low nibble (waves 14,15 = 0
// = sim waves). SIMD s hosts waves {s,s+4,s+8,s+12}:
//   S0 {0,4,8,12} = 4+4+4+4 = 16
//   S1 {1,5,9,13} = 4+4+4+4 = 16
//   S2 {2,6,10}   = 2+2+2   =  6  (+ r0-chain wave 14)
//   S3 {3,7,11}   = 4+4+4   = 12  (+ si wave 15)
// ADDITIVE model (fit r19+r21): T_chainSIMD = 190U+1800, T_siSIMD = 190U+800,
// T_genSIMD = 190U — chain serial latency does NOT overlap co-resident gen
// issue. Integer optimum {6,12,16,16}: max ~3080 cy (r19's {7,13,15,15} gave
// 3270; r21's {11,10,15,14} gave 3850 — both match the model).
#define CNTPACK 0x44424442444244ULL

typedef float f32x4 __attribute__((ext_vector_type(4)));

__device__ __forceinline__ uint32_t rotl32(uint32_t v, int d) {
  return __builtin_rotateleft32(v, (uint32_t)d);
}

// JAX threefry2x32, 20 rounds.
__device__ __forceinline__ void tf2x32(uint32_t k0, uint32_t k1,
                                       uint32_t x0, uint32_t x1,
                                       uint32_t& o0, uint32_t& o1) {
  uint32_t ks2 = k0 ^ k1 ^ 0x1BD11BDAu;
#define TF_ROUND(r) { x0 += x1; x1 = rotl32(x1, r); x1 ^= x0; }
  x0 += k0; x1 += k1;
  TF_ROUND(13) TF_ROUND(15) TF_ROUND(26) TF_ROUND(6)
  x0 += k1; x1 += ks2 + 1u;
  TF_ROUND(17) TF_ROUND(29) TF_ROUND(16) TF_ROUND(24)
  x0 += ks2; x1 += k0 + 2u;
  TF_ROUND(13) TF_ROUND(15) TF_ROUND(26) TF_ROUND(6)
  x0 += k0; x1 += k1 + 3u;
  TF_ROUND(17) TF_ROUND(29) TF_ROUND(16) TF_ROUND(24)
  x0 += k1; x1 += ks2 + 4u;
  TF_ROUND(13) TF_ROUND(15) TF_ROUND(26) TF_ROUND(6)
  x0 += ks2; x1 += k0 + 5u;
#undef TF_ROUND
  o0 = x0; o1 = x1;
}

// jax.random.split(key(seed)), jax_threefry_partitionable=True (fold-like).
__device__ __forceinline__ void derive_keys(int seed, uint32_t& kn0, uint32_t& kn1,
                                            uint32_t& ku0, uint32_t& ku1) {
  uint64_t sv = (uint64_t)(int64_t)seed;
  uint32_t k0 = (uint32_t)(sv >> 32);
  uint32_t k1 = (uint32_t)(sv & 0xffffffffULL);
  tf2x32(k0, k1, 0u, 0u, kn0, kn1);  // keys[0] = k_noise
  tf2x32(k0, k1, 0u, 1u, ku0, ku1);  // keys[1] = k_u
}

// partitionable random_bits(32): counter = (hi=0, lo=n); bits = y0 ^ y1.
__device__ __forceinline__ uint32_t rand_bits32(uint32_t k0, uint32_t k1, uint32_t n) {
  uint32_t y0, y1;
  tf2x32(k0, k1, 0u, n, y0, y1);
  return y0 ^ y1;
}

// bits -> erfinv-core p*u (XLA ErfInv32/Giles). Caller multiplies by
// cpv = (0.1*sqrt(2))*pvol — validated bit-compatible since r8.
__device__ __forceinline__ float bits_to_eu(uint32_t bits) {
#pragma clang fp contract(fast)
  float u01 = __uint_as_float((bits >> 9) | 0x3f800000u) - 1.0f;
  float u = u01 * 2.0f + (-0.99999994f);
  u = fmaxf(-0.99999994f, u);
  float omu2 = 1.0f - u * u;                       // fma(-u,u,1)
  float w = -(__builtin_amdgcn_logf(omu2) * 0.6931472f);  // v_log (log2) * ln2
  float p;
  if (w < 5.0f) {
    float z = w - 2.5f;
    p = 2.81022636e-08f;
    p = 3.43273939e-07f + p * z;
    p = -3.5233877e-06f + p * z;
    p = -4.39150654e-06f + p * z;
    p = 0.00021858087f + p * z;
    p = -0.00125372503f + p * z;
    p = -0.00417768164f + p * z;
    p = 0.246640727f + p * z;
    p = 1.50140941f + p * z;
  } else {
    float z = __builtin_amdgcn_sqrtf(w) - 3.0f;
    p = -0.000200214257f;
    p = 0.000100950558f + p * z;
    p = 0.00134934322f + p * z;
    p = -0.00367342844f + p * z;
    p = 0.00573950773f + p * z;
    p = -0.0076224613f + p * z;
    p = 0.00943887047f + p * z;
    p = 1.00167406f + p * z;
    p = 2.83297682f + p * z;
  }
  return p * u;
}

__device__ __forceinline__ float clip_param(float x) {
  return fminf(0.99999988f, fmaxf(1e-07f, x));
}

// Fused, barrier-free, static schedule (r19 structure, r22 unit counts).
// 256 blocks x 16 waves: gen waves 0..13 fill a 6-deep LDS noise ring;
// wave 14 (S2) runs the serial r0 chain into a 2-deep rbuf; wave 15 (S3)
// runs s,i + summarize. Monotone counters + s_sleep spins.
__global__ __launch_bounds__(1024) void fused_kernel(const float* __restrict__ cond,
                                                     const int* __restrict__ seedp,
                                                     float* __restrict__ out) {
  __shared__ f32x4 nbuf[NDEPTH][25][TRAJ];  // 76.8 KiB: noise ring
  __shared__ f32x4 rbuf[2][25][TRAJ];       // 25.6 KiB: exiting-r0, 2 groups
  __shared__ int done[TSAVES];              // gen waves finished with group g (of 14)
  __shared__ int r0cnt, sicnt;

  const int tid = threadIdx.x;
  const int lane = tid & 63;
  const int wv = tid >> 6;
  const int bbase = blockIdx.x * TRAJ;
  const int tr = lane & 31;
  const int h = lane >> 5;              // gen: e-parity selector
  const int b = bbase + tr;

  if (tid < TSAVES) done[tid] = 0;
  if (tid == 0) { r0cnt = 0; sicnt = 0; }
  __syncthreads();

  volatile int* vdone = done;
  volatile int* vr0 = &r0cnt;
  volatile int* vsi = &sicnt;

  uint32_t kn0, kn1, ku0, ku1;
  derive_keys(seedp[0], kn0, kn1, ku0, ku1);

  float pinf = clip_param(cond[b * 4 + 0]);
  float prec = clip_param(cond[b * 4 + 1]);
  float pmr  = clip_param(cond[b * 4 + 2]);
  float pvol = clip_param(cond[b * 4 + 3]);
  const float r0m  = pinf / prec;
  const float dtmr = 0.01f * pmr;
  const float c4 = 1.0f - dtmr;
  const float a4 = dtmr * r0m;
  const float c2 = 0.01f * prec;
  const float c3 = 1.0f - c2;
  const float c3p4 = (c3 * c3) * (c3 * c3);
  const float cpv = 0.14142136f * pvol;     // 0.1*sqrt(2) folded (r8+)

  if (wv < GENW) {
    // -------- producers: static units per CNTPACK --------
    const int cnt = (int)((CNTPACK >> (4 * wv)) & 0xFULL);
    int off = 0;
#pragma unroll
    for (int w = 0; w < GENW; ++w) if (w < wv) off += (int)((CNTPACK >> (4 * w)) & 0xFULL);
    for (int g = 0; g <= 48; ++g) {
      if (g >= NDEPTH) {                   // ring slot free when chain did g-NDEPTH
        while (*vr0 < g - (NDEPTH - 1)) __builtin_amdgcn_s_sleep(1);
      }
      const uint32_t nbase = (uint32_t)(g * SPSAVE) * (uint32_t)NB + (uint32_t)b;
      float* nb = (float*)&nbuf[g % NDEPTH][0][0];
      for (int k = 0; k < cnt; ++k) {
        const int id = off + k;            // 0..49 chunk-halves
        const int c = id >> 1;
        const int e = ((id & 1) << 1) | h;
        uint32_t n = nbase + (uint32_t)(4 * c + e) * (uint32_t)NB;
        float eu = bits_to_eu(rand_bits32(kn0, kn1, n));
        nb[(c * 32 + tr) * 4 + e] = eu * cpv;
      }
      __threadfence_block();               // drain ds_writes before signaling
      if (lane == 0) atomicAdd(&done[g], 1);
    }
  } else if (wv == GENW) {
    // -------- r0 chain (serial latency floor; S2 carries only 6 gen units) --------
    float r0 = r0m;
    for (int g = 0; g <= 48; ++g) {
      while (vdone[g] < GENW) __builtin_amdgcn_s_sleep(1);
      if (g >= 2) {                        // rbuf[g&1] reusable when si did g-2
        while (*vsi < g - 1) __builtin_amdgcn_s_sleep(1);
      }
      __threadfence_block();               // acquire
      const int sn = g % NDEPTH, sr = g & 1;
      f32x4 vd = nbuf[sn][0][tr];
#pragma unroll
      for (int c = 0; c < 25; ++c) {
        f32x4 vdn = (c < 24) ? nbuf[sn][c + 1][tr] : vd;  // prefetch next
        f32x4 w;
#pragma unroll
        for (int e = 0; e < 4; ++e) {
          float sq  = __builtin_amdgcn_sqrtf(fabsf(r0));
          float r0h = fmaf(c4, r0, a4);
          r0 = fmaf(sq, vd[e], r0h);
          w[e] = r0;                        // exiting r0
        }
        rbuf[sr][c][tr] = w;
        vd = vdn;
      }
      __threadfence_block();               // release
      if (lane == 0) *vr0 = g + 1;
    }
  } else {
    // -------- s,i + streaming summarize (S3, 12 gen units) --------
    float s = 0.99f, i = 0.01f, r0in = r0m;
    float best = -1.0f; int bi = 0;
    float plg = 0.0f, sd = 0.0f, sd2 = 0.0f;
    for (int g = 0; g <= 48; ++g) {
      while (*vr0 < g + 1) __builtin_amdgcn_s_sleep(1);
      __threadfence_block();               // acquire
      const int sr = g & 1;
      f32x4 rv = rbuf[sr][0][tr];
#pragma unroll
      for (int c = 0; c < 25; ++c) {
        f32x4 rvn = (c < 24) ? rbuf[sr][c + 1][tr] : rv;  // prefetch next
        float rs0 = r0in * s;  s = fmaf(-c2, rs0, s);
        float rs1 = rv[0] * s; s = fmaf(-c2, rs1, s);
        float rs2 = rv[1] * s; s = fmaf(-c2, rs2, s);
        float rs3 = rv[2] * s; s = fmaf(-c2, rs3, s);
        float hh = fmaf(c3, rs0, rs1);
        hh = fmaf(c3, hh, rs2);
        hh = fmaf(c3, hh, rs3);
        i = fmaf(c3p4, i, c2 * hh);
        r0in = rv[3];
        rv = rvn;
      }
      float v = i;
      if (!isfinite(v)) v = 0.0f;
      float x = fmaxf(v, 1e-05f);
      if (x > best) { best = x; bi = g; }
      float lg = __builtin_amdgcn_logf(x) * 0.6931472f;
      if (g > 0) { float d = lg - plg; sd += d; sd2 += d * d; }
      plg = lg;
      __threadfence_block();               // release (done reading rbuf[sr])
      if (lane == 0) *vsi = g + 1;
    }
    if (lane < TRAJ) {
      uint32_t ub = rand_bits32(ku0, ku1, (uint32_t)b);
      float u = __uint_as_float((ub >> 9) | 0x3f800000u) - 1.0f;
      u = fmaxf(0.0f, u);
      float maxat = ((float)bi + u) / 49.0f;
      float mean = sd / 48.0f;
      float var = sd2 / 48.0f - mean * mean;
      float stdv = sqrtf(fmaxf(var, 0.0f));
      out[b * 3 + 0] = (best  - 0.38f) / 0.14f;
      out[b * 3 + 1] = (maxat - 0.21f) / 0.12f;
      out[b * 3 + 2] = (stdv  - 0.14f) / 0.03f;
    }
  }
}

extern "C" void kernel_launch(void* const* d_in, const int* in_sizes, int n_in,
                              void* d_out, int out_size, void* d_ws, size_t ws_size,
                              hipStream_t stream) {
  const float* cond = (const float*)d_in[0];
  const int* seedp = (const int*)d_in[1];
  float* out = (float*)d_out;
  (void)d_ws; (void)ws_size;   // fully LDS-resident: no workspace needed
  fused_kernel<<<NB / TRAJ, 1024, 0, stream>>>(cond, seedp, out);
}

// Round 23
// 131.325 us; speedup vs baseline: 1.1531x; 1.0909x over previous
//
#include <hip/hip_runtime.h>
#include <cstdint>

// XLA emits separate mul/add; contraction off by default. Hot paths use
// explicit fmaf()/hw-transcendentals — measured-safe across 19 rounds
// (absmax pinned at 3.36e7 vs threshold 4.76e34 for r8-r22's variants).
#pragma clang fp contract(off)

#define TSAVES 49
#define SPSAVE 100
#define NB 8192
#define TRAJ 32                    // trajectories per block
#define GENW 14                    // noise-generator waves per block
#define NDEPTH 6                   // noise ring depth (gen run-ahead)

// Per-wave gen-unit counts, nibble-packed, w0 in low nibble. SIMD s hosts
// waves {s, s+4, s+8, s+12}: S0 {0,4,8,12}=4+4+4+3=15, S1 {1,5,9,13}=15,
// S2 {2,6,10}=3+2+2=7 (+r0 chain wave 14), S3 {3,7,11}=5+4+4=13 (+si).
// MEASURED-OPTIMAL (r19: 131 us). Controlled deviations both regressed:
// r21 {11,10,15,14}=151, r22 {6,12,16,16}=143. Total VALU work/group/CU
// ~13.3k cy over 4 SIMDs -> floor ~3325 cy; r19 runs 3375 (91% VALUBusy)
// = within ~2% of the balanced-issue roofline for this bit-exact workload.
#define CNTPACK 0x33424442445344ULL

typedef float f32x4 __attribute__((ext_vector_type(4)));

__device__ __forceinline__ uint32_t rotl32(uint32_t v, int d) {
  return __builtin_rotateleft32(v, (uint32_t)d);
}

// JAX threefry2x32, 20 rounds.
__device__ __forceinline__ void tf2x32(uint32_t k0, uint32_t k1,
                                       uint32_t x0, uint32_t x1,
                                       uint32_t& o0, uint32_t& o1) {
  uint32_t ks2 = k0 ^ k1 ^ 0x1BD11BDAu;
#define TF_ROUND(r) { x0 += x1; x1 = rotl32(x1, r); x1 ^= x0; }
  x0 += k0; x1 += k1;
  TF_ROUND(13) TF_ROUND(15) TF_ROUND(26) TF_ROUND(6)
  x0 += k1; x1 += ks2 + 1u;
  TF_ROUND(17) TF_ROUND(29) TF_ROUND(16) TF_ROUND(24)
  x0 += ks2; x1 += k0 + 2u;
  TF_ROUND(13) TF_ROUND(15) TF_ROUND(26) TF_ROUND(6)
  x0 += k0; x1 += k1 + 3u;
  TF_ROUND(17) TF_ROUND(29) TF_ROUND(16) TF_ROUND(24)
  x0 += k1; x1 += ks2 + 4u;
  TF_ROUND(13) TF_ROUND(15) TF_ROUND(26) TF_ROUND(6)
  x0 += ks2; x1 += k0 + 5u;
#undef TF_ROUND
  o0 = x0; o1 = x1;
}

// jax.random.split(key(seed)), jax_threefry_partitionable=True (fold-like).
__device__ __forceinline__ void derive_keys(int seed, uint32_t& kn0, uint32_t& kn1,
                                            uint32_t& ku0, uint32_t& ku1) {
  uint64_t sv = (uint64_t)(int64_t)seed;
  uint32_t k0 = (uint32_t)(sv >> 32);
  uint32_t k1 = (uint32_t)(sv & 0xffffffffULL);
  tf2x32(k0, k1, 0u, 0u, kn0, kn1);  // keys[0] = k_noise
  tf2x32(k0, k1, 0u, 1u, ku0, ku1);  // keys[1] = k_u
}

// partitionable random_bits(32): counter = (hi=0, lo=n); bits = y0 ^ y1.
__device__ __forceinline__ uint32_t rand_bits32(uint32_t k0, uint32_t k1, uint32_t n) {
  uint32_t y0, y1;
  tf2x32(k0, k1, 0u, n, y0, y1);
  return y0 ^ y1;
}

// bits -> erfinv-core p*u (XLA ErfInv32/Giles). Caller multiplies by
// cpv = (0.1*sqrt(2))*pvol — validated bit-compatible since r8.
__device__ __forceinline__ float bits_to_eu(uint32_t bits) {
#pragma clang fp contract(fast)
  float u01 = __uint_as_float((bits >> 9) | 0x3f800000u) - 1.0f;
  float u = u01 * 2.0f + (-0.99999994f);
  u = fmaxf(-0.99999994f, u);
  float omu2 = 1.0f - u * u;                       // fma(-u,u,1)
  float w = -(__builtin_amdgcn_logf(omu2) * 0.6931472f);  // v_log (log2) * ln2
  float p;
  if (w < 5.0f) {
    float z = w - 2.5f;
    p = 2.81022636e-08f;
    p = 3.43273939e-07f + p * z;
    p = -3.5233877e-06f + p * z;
    p = -4.39150654e-06f + p * z;
    p = 0.00021858087f + p * z;
    p = -0.00125372503f + p * z;
    p = -0.00417768164f + p * z;
    p = 0.246640727f + p * z;
    p = 1.50140941f + p * z;
  } else {
    float z = __builtin_amdgcn_sqrtf(w) - 3.0f;
    p = -0.000200214257f;
    p = 0.000100950558f + p * z;
    p = 0.00134934322f + p * z;
    p = -0.00367342844f + p * z;
    p = 0.00573950773f + p * z;
    p = -0.0076224613f + p * z;
    p = 0.00943887047f + p * z;
    p = 1.00167406f + p * z;
    p = 2.83297682f + p * z;
  }
  return p * u;
}

__device__ __forceinline__ float clip_param(float x) {
  return fminf(0.99999988f, fmaxf(1e-07f, x));
}

// Fused, barrier-free, static schedule, SIMD-rebalanced (see CNTPACK note).
// 256 blocks x 16 waves. Gen waves 0..13 fill a 6-deep LDS noise ring;
// wave 14 runs the serial r0 chain; wave 15 runs s,i + summarize.
// Monotone counters + s_sleep spins (r15/r17/r19-validated).
__global__ __launch_bounds__(1024) void fused_kernel(const float* __restrict__ cond,
                                                     const int* __restrict__ seedp,
                                                     float* __restrict__ out) {
  __shared__ f32x4 nbuf[NDEPTH][25][TRAJ];  // 76.8 KiB: noise ring
  __shared__ f32x4 rbuf[2][25][TRAJ];       // 25.6 KiB: exiting-r0, 2 groups
  __shared__ int done[TSAVES];              // gen waves finished with group g (of 14)
  __shared__ int r0cnt, sicnt;

  const int tid = threadIdx.x;
  const int lane = tid & 63;
  const int wv = tid >> 6;
  const int bbase = blockIdx.x * TRAJ;
  const int tr = lane & 31;
  const int h = lane >> 5;              // gen: e-parity selector
  const int b = bbase + tr;

  if (tid < TSAVES) done[tid] = 0;
  if (tid == 0) { r0cnt = 0; sicnt = 0; }
  __syncthreads();

  volatile int* vdone = done;
  volatile int* vr0 = &r0cnt;
  volatile int* vsi = &sicnt;

  uint32_t kn0, kn1, ku0, ku1;
  derive_keys(seedp[0], kn0, kn1, ku0, ku1);

  float pinf = clip_param(cond[b * 4 + 0]);
  float prec = clip_param(cond[b * 4 + 1]);
  float pmr  = clip_param(cond[b * 4 + 2]);
  float pvol = clip_param(cond[b * 4 + 3]);
  const float r0m  = pinf / prec;
  const float dtmr = 0.01f * pmr;
  const float c4 = 1.0f - dtmr;
  const float a4 = dtmr * r0m;
  const float c2 = 0.01f * prec;
  const float c3 = 1.0f - c2;
  const float c3p4 = (c3 * c3) * (c3 * c3);
  const float cpv = 0.14142136f * pvol;     // 0.1*sqrt(2) folded (r8+)

  if (wv < GENW) {
    // -------- producers: rebalanced static units --------
    const int cnt = (int)((CNTPACK >> (4 * wv)) & 0xFULL);
    int off = 0;
#pragma unroll
    for (int w = 0; w < GENW; ++w) if (w < wv) off += (int)((CNTPACK >> (4 * w)) & 0xFULL);
    for (int g = 0; g <= 48; ++g) {
      if (g >= NDEPTH) {                   // ring slot free when chain did g-NDEPTH
        while (*vr0 < g - (NDEPTH - 1)) __builtin_amdgcn_s_sleep(1);
      }
      const uint32_t nbase = (uint32_t)(g * SPSAVE) * (uint32_t)NB + (uint32_t)b;
      float* nb = (float*)&nbuf[g % NDEPTH][0][0];
      for (int k = 0; k < cnt; ++k) {
        const int id = off + k;            // 0..49 chunk-halves
        const int c = id >> 1;
        const int e = ((id & 1) << 1) | h;
        uint32_t n = nbase + (uint32_t)(4 * c + e) * (uint32_t)NB;
        float eu = bits_to_eu(rand_bits32(kn0, kn1, n));
        nb[(c * 32 + tr) * 4 + e] = eu * cpv;
      }
      __threadfence_block();               // drain ds_writes before signaling
      if (lane == 0) atomicAdd(&done[g], 1);
    }
  } else if (wv == GENW) {
    // -------- r0 chain (serial latency floor; lightly-loaded SIMD2) --------
    float r0 = r0m;
    for (int g = 0; g <= 48; ++g) {
      while (vdone[g] < GENW) __builtin_amdgcn_s_sleep(1);
      if (g >= 2) {                        // rbuf[g&1] reusable when si did g-2
        while (*vsi < g - 1) __builtin_amdgcn_s_sleep(1);
      }
      __threadfence_block();               // acquire
      const int sn = g % NDEPTH, sr = g & 1;
      f32x4 vd = nbuf[sn][0][tr];
#pragma unroll
      for (int c = 0; c < 25; ++c) {
        f32x4 vdn = (c < 24) ? nbuf[sn][c + 1][tr] : vd;  // prefetch next
        f32x4 w;
#pragma unroll
        for (int e = 0; e < 4; ++e) {
          float sq  = __builtin_amdgcn_sqrtf(fabsf(r0));
          float r0h = fmaf(c4, r0, a4);
          r0 = fmaf(sq, vd[e], r0h);
          w[e] = r0;                        // exiting r0
        }
        rbuf[sr][c][tr] = w;
        vd = vdn;
      }
      __threadfence_block();               // release
      if (lane == 0) *vr0 = g + 1;
    }
  } else {
    // -------- s,i + streaming summarize (SIMD3) --------
    float s = 0.99f, i = 0.01f, r0in = r0m;
    float best = -1.0f; int bi = 0;
    float plg = 0.0f, sd = 0.0f, sd2 = 0.0f;
    for (int g = 0; g <= 48; ++g) {
      while (*vr0 < g + 1) __builtin_amdgcn_s_sleep(1);
      __threadfence_block();               // acquire
      const int sr = g & 1;
      f32x4 rv = rbuf[sr][0][tr];
#pragma unroll
      for (int c = 0; c < 25; ++c) {
        f32x4 rvn = (c < 24) ? rbuf[sr][c + 1][tr] : rv;  // prefetch next
        float rs0 = r0in * s;  s = fmaf(-c2, rs0, s);
        float rs1 = rv[0] * s; s = fmaf(-c2, rs1, s);
        float rs2 = rv[1] * s; s = fmaf(-c2, rs2, s);
        float rs3 = rv[2] * s; s = fmaf(-c2, rs3, s);
        float hh = fmaf(c3, rs0, rs1);
        hh = fmaf(c3, hh, rs2);
        hh = fmaf(c3, hh, rs3);
        i = fmaf(c3p4, i, c2 * hh);
        r0in = rv[3];
        rv = rvn;
      }
      float v = i;
      if (!isfinite(v)) v = 0.0f;
      float x = fmaxf(v, 1e-05f);
      if (x > best) { best = x; bi = g; }
      float lg = __builtin_amdgcn_logf(x) * 0.6931472f;
      if (g > 0) { float d = lg - plg; sd += d; sd2 += d * d; }
      plg = lg;
      __threadfence_block();               // release (done reading rbuf[sr])
      if (lane == 0) *vsi = g + 1;
    }
    if (lane < TRAJ) {
      uint32_t ub = rand_bits32(ku0, ku1, (uint32_t)b);
      float u = __uint_as_float((ub >> 9) | 0x3f800000u) - 1.0f;
      u = fmaxf(0.0f, u);
      float maxat = ((float)bi + u) / 49.0f;
      float mean = sd / 48.0f;
      float var = sd2 / 48.0f - mean * mean;
      float stdv = sqrtf(fmaxf(var, 0.0f));
      out[b * 3 + 0] = (best  - 0.38f) / 0.14f;
      out[b * 3 + 1] = (maxat - 0.21f) / 0.12f;
      out[b * 3 + 2] = (stdv  - 0.14f) / 0.03f;
    }
  }
}

extern "C" void kernel_launch(void* const* d_in, const int* in_sizes, int n_in,
                              void* d_out, int out_size, void* d_ws, size_t ws_size,
                              hipStream_t stream) {
  const float* cond = (const float*)d_in[0];
  const int* seedp = (const int*)d_in[1];
  float* out = (float*)d_out;
  (void)d_ws; (void)ws_size;   // fully LDS-resident: no workspace needed
  fused_kernel<<<NB / TRAJ, 1024, 0, stream>>>(cond, seedp, out);
}